// Round 2
// baseline (1404.179 us; speedup 1.0000x reference)
//
#include <hip/hip_runtime.h>
#include <math.h>

#define NN 50000
#define NE 512000
#define NE2 256000
#define SCALE 0.17677669529663687f   // 1/sqrt(32)
#define EPSV 1e-5f

// ---- workspace layout (float offsets) ----
// region1 (dead after pass2, then aliased):
#define OFF_Q      0UL          // 50000*128
#define OFF_K      6400000UL
#define OFF_V      12800000UL
//   aliases (used after pass2):
#define OFF_ATTR   0UL          // 50000*32
#define OFF_O1     1600000UL
#define OFF_XGAT   3200000UL
#define OFF_O1ACC  4800000UL
#define OFF_DEGB   6400000UL    // 50000
#define OFF_STATS  6450000UL    // 64
// region2:
#define OFF_EX1    19200000UL   // 512000*4
#define OFF_EX2    21248000UL
#define OFF_S1     31488000UL   // 50000*4   (zero region start)
#define OFF_S2     31688000UL
//   alias: xh = region2 start (256000*32 floats = 8.192M)
#define OFF_XH     19200000UL
// region3:
#define OFF_AGG    31888000UL   // 50000*128  (zero region end = 38288000)
// region4:
#define OFF_WBT    38288000UL   // bf16 256*128 = 16384 floats
#define OFF_BIASB  38304384UL   // 256 floats
// total: 38304640 floats = 153.2 MB

typedef __attribute__((ext_vector_type(8))) short bf16x8;
typedef __attribute__((ext_vector_type(8))) unsigned short us8;
typedef __attribute__((ext_vector_type(4))) float f32x4;

#define ESTRIDE 136   // Es row stride in ushorts (128 data + 8 pad)

__device__ __forceinline__ unsigned short f2bf(float f) {
    unsigned int u = __float_as_uint(f);
    unsigned int r = (u + 0x7FFFu + ((u >> 16) & 1u)) >> 16;
    return (unsigned short)r;
}
__device__ __forceinline__ float bf2f(unsigned short u) {
    return __uint_as_float(((unsigned int)u) << 16);
}

// ---------------- pack WbT (transposed, bf16) + biasb ----------------
// WbT[j][k] = (j<128 ? We2 : We3)[k][j%128], j=0..255, k=0..127
__global__ void pack_w(const float* __restrict__ We2, const float* __restrict__ be2,
                       const float* __restrict__ We3, const float* __restrict__ be3,
                       unsigned short* __restrict__ WbT, float* __restrict__ biasb) {
    const int idx = blockIdx.x * 256 + threadIdx.x;
    if (idx < 32768) {
        const int j = idx >> 7;
        const int k = idx & 127;
        const float w = (j < 128) ? We2[k * 128 + j] : We3[k * 128 + (j - 128)];
        WbT[idx] = f2bf(w);
    } else if (idx < 33024) {
        const int jj = idx - 32768;
        biasb[jj] = (jj < 128) ? be2[jj] : be3[jj - 128];
    }
}

// ---------------- shared GEMM tile: Es(128x128 bf16, stride ESTRIDE) = A_tile @ W_half + bias --------
// sh must be >= 18432 ushorts. As = sh[0:9216], Bs = sh[9216:18432], Es overlays sh (17408 ushorts).
__device__ __forceinline__ void gemm_tile(const float* __restrict__ A,
                                          const unsigned short* __restrict__ WbT,
                                          const float* __restrict__ biasb, const int half,
                                          unsigned short* sh, const size_t r0, const int tid) {
    unsigned short* As = sh;          // stride 72
    unsigned short* Bs = sh + 9216;   // stride 72
    const int wave = tid >> 6;
    const int lane = tid & 63;
    const int quad = lane >> 4;
    const int l16 = lane & 15;
    const int m0 = (wave & 1) * 64;
    const int n0 = (wave >> 1) * 64;

    f32x4 acc[4][4];
    #pragma unroll
    for (int i = 0; i < 4; i++)
        #pragma unroll
        for (int j = 0; j < 4; j++) acc[i][j] = (f32x4){0.f, 0.f, 0.f, 0.f};

    for (int kh = 0; kh < 2; kh++) {
        // stage A half: 128 rows x 64 cols fp32 -> bf16
        #pragma unroll
        for (int i = 0; i < 8; i++) {
            const int q = tid + 256 * i;
            const int row = q >> 4;
            const int c4 = q & 15;
            const float4 a4 = *(const float4*)(A + (r0 + row) * 128 + kh * 64 + c4 * 4);
            ushort4 b4;
            b4.x = f2bf(a4.x); b4.y = f2bf(a4.y); b4.z = f2bf(a4.z); b4.w = f2bf(a4.w);
            *(ushort4*)(&As[row * 72 + c4 * 4]) = b4;
        }
        // stage B half: Bs[n][k] from WbT[(half*128+n)*128 + kh*64 + k]
        {
            const int n = tid >> 1;
            const int koff = (tid & 1) * 32;
            const unsigned short* src = WbT + (size_t)(half * 128 + n) * 128 + kh * 64 + koff;
            #pragma unroll
            for (int u = 0; u < 4; u++) {
                *(us8*)(&Bs[n * 72 + koff + 8 * u]) = *(const us8*)(src + 8 * u);
            }
        }
        __syncthreads();
        #pragma unroll
        for (int kc = 0; kc < 64; kc += 32) {
            bf16x8 af[4], bf[4];
            #pragma unroll
            for (int i = 0; i < 4; i++)
                af[i] = *(const bf16x8*)(&As[(m0 + 16 * i + l16) * 72 + kc + quad * 8]);
            #pragma unroll
            for (int j = 0; j < 4; j++)
                bf[j] = *(const bf16x8*)(&Bs[(n0 + 16 * j + l16) * 72 + kc + quad * 8]);
            #pragma unroll
            for (int i = 0; i < 4; i++)
                #pragma unroll
                for (int j = 0; j < 4; j++)
                    acc[i][j] = __builtin_amdgcn_mfma_f32_16x16x32_bf16(af[i], bf[j], acc[i][j], 0, 0, 0);
        }
        __syncthreads();   // As/Bs reads done; safe to overwrite (next kh stage or Es below)
    }
    // write tile (+bias, bf16) into Es overlay
    #pragma unroll
    for (int j = 0; j < 4; j++) {
        const int col = n0 + 16 * j + l16;
        const float bcol = biasb[half * 128 + col];
        #pragma unroll
        for (int i = 0; i < 4; i++) {
            #pragma unroll
            for (int r = 0; r < 4; r++) {
                const int row = m0 + 16 * i + quad * 4 + r;
                sh[row * ESTRIDE + col] = f2bf(acc[i][j][r] + bcol);
            }
        }
    }
    __syncthreads();   // Es visible to all waves
}

// ---------------- fused: ea2 tile + pass1 (logits -> ex, s atomics) ----------------
__global__ __launch_bounds__(256)
void gemm_pass1(const float* __restrict__ eatt, const unsigned short* __restrict__ WbT,
                const float* __restrict__ biasb, const int* __restrict__ eidx,
                const float* __restrict__ q, const float* __restrict__ k,
                float* __restrict__ ex1, float* __restrict__ ex2,
                float* __restrict__ s1, float* __restrict__ s2) {
    __shared__ unsigned short sh[18432];
    const int tid = threadIdx.x;
    const size_t r0 = (size_t)blockIdx.x * 128;
    gemm_tile(eatt, WbT, biasb, 0, sh, r0, tid);

    const int wave = tid >> 6;
    const int lane = tid & 63;
    for (int t = 0; t < 32; t++) {
        const int lrow = wave * 32 + t;
        const size_t e = r0 + lrow;
        const int src = eidx[e];
        const int dst = eidx[NE + e];
        const float2 qv = ((const float2*)(q + (size_t)dst * 128))[lane];
        const float2 kv = ((const float2*)(k + (size_t)src * 128))[lane];
        const unsigned int cc = *(const unsigned int*)(&sh[lrow * ESTRIDE + lane * 2]);
        const float ea2a = bf2f((unsigned short)(cc & 0xFFFF));
        const float ea2b = bf2f((unsigned short)(cc >> 16));
        float p1 = qv.x * kv.x + qv.y * kv.y;
        float p2 = qv.x * ea2a + qv.y * ea2b;
        #pragma unroll
        for (int off = 8; off > 0; off >>= 1) {
            p1 += __shfl_down(p1, off, 16);
            p2 += __shfl_down(p2, off, 16);
        }
        if ((lane & 15) == 0) {
            const int h = lane >> 4;
            const float v1 = __expf(p1 * SCALE);
            const float v2 = __expf(p2 * SCALE);
            ex1[e * 4 + h] = v1;
            ex2[e * 4 + h] = v2;
            atomicAdd(&s1[(size_t)dst * 4 + h], v1);
            atomicAdd(&s2[(size_t)dst * 4 + h], v2);
        }
    }
}

// ---------------- fused: ea3 tile + pass2 (msg scatter into agg) ----------------
__global__ __launch_bounds__(256)
void gemm_pass2(const float* __restrict__ eatt, const unsigned short* __restrict__ WbT,
                const float* __restrict__ biasb, const int* __restrict__ eidx,
                const float* __restrict__ v,
                const float* __restrict__ ex1, const float* __restrict__ ex2,
                const float* __restrict__ s1, const float* __restrict__ s2,
                float* __restrict__ agg) {
    __shared__ unsigned short sh[18432];
    const int tid = threadIdx.x;
    const size_t r0 = (size_t)blockIdx.x * 128;
    gemm_tile(eatt, WbT, biasb, 1, sh, r0, tid);

    const int wave = tid >> 6;
    const int lane = tid & 63;
    for (int t = 0; t < 32; t++) {
        const int lrow = wave * 32 + t;
        const size_t e = r0 + lrow;
        const int src = eidx[e];
        const int dst = eidx[NE + e];
        float a1l = 0.f, a2l = 0.f;
        if (lane < 4) {
            a1l = ex1[e * 4 + lane] / (s1[(size_t)dst * 4 + lane] + 1e-16f);
            a2l = ex2[e * 4 + lane] / (s2[(size_t)dst * 4 + lane] + 1e-16f);
        }
        const int h1 = lane >> 5;          // head of channel lane
        const int h2 = 2 + (lane >> 5);    // head of channel lane+64
        const float a1c1 = __shfl(a1l, h1), a1c2 = __shfl(a1l, h2);
        const float a2c1 = __shfl(a2l, h1), a2c2 = __shfl(a2l, h2);
        const float vv1 = v[(size_t)src * 128 + lane];
        const float vv2 = v[(size_t)src * 128 + lane + 64];
        const float e31 = bf2f(sh[lrow * ESTRIDE + lane]);
        const float e32 = bf2f(sh[lrow * ESTRIDE + lane + 64]);
        atomicAdd(&agg[(size_t)dst * 128 + lane],      a1c1 * vv1 + a2c1 * e31);
        atomicAdd(&agg[(size_t)dst * 128 + lane + 64], a1c2 * vv2 + a2c2 * e32);
    }
}

// ---------------- K1: q,k,v = x @ W{q,k,v} + b ----------------
__global__ void qkv_kernel(const float* __restrict__ x,
                           const float* __restrict__ Wq, const float* __restrict__ bq,
                           const float* __restrict__ Wk, const float* __restrict__ bk,
                           const float* __restrict__ Wv, const float* __restrict__ bv,
                           float* __restrict__ q, float* __restrict__ k, float* __restrict__ v) {
    __shared__ float xs[8 * 128];
    const int tid = threadIdx.x;
    const int j = tid & 127;
    const int g = tid >> 7;
    const size_t n0 = (size_t)blockIdx.x * 8;
    ((float4*)xs)[tid] = ((const float4*)(x + n0 * 128))[tid];
    __syncthreads();
    float aq[4] = {0,0,0,0}, ak[4] = {0,0,0,0}, av[4] = {0,0,0,0};
    #pragma unroll 4
    for (int d = 0; d < 128; d++) {
        const float wq = Wq[d*128 + j];
        const float wk = Wk[d*128 + j];
        const float wv = Wv[d*128 + j];
        #pragma unroll
        for (int r = 0; r < 4; r++) {
            const float xv = xs[(g + 2*r)*128 + d];
            aq[r] += xv * wq; ak[r] += xv * wk; av[r] += xv * wv;
        }
    }
    const float bqv = bq[j], bkv = bk[j], bvv = bv[j];
    #pragma unroll
    for (int r = 0; r < 4; r++) {
        const size_t n = n0 + g + 2*r;
        q[n*128 + j] = aq[r] + bqv;
        k[n*128 + j] = ak[r] + bkv;
        v[n*128 + j] = av[r] + bvv;
    }
}

// ---------------- generic (M x 128) @ (128 x 32) ----------------
__global__ void gemm_d128_o32(const float* __restrict__ A, const float* __restrict__ W,
                              float* __restrict__ out) {
    __shared__ float as[8 * 128];
    const int tid = threadIdx.x;
    const int p = tid & 31;
    const int mm = tid >> 5;
    const size_t m0 = (size_t)blockIdx.x * 8;
    ((float4*)as)[tid] = ((const float4*)(A + m0 * 128))[tid];
    __syncthreads();
    float c0 = 0.f, c1 = 0.f, c2 = 0.f, c3 = 0.f;
    const float4* as4 = (const float4*)as;
    #pragma unroll 8
    for (int i = 0; i < 32; i++) {
        const float4 a4 = as4[mm*32 + i];
        c0 += a4.x * W[(4*i+0)*32 + p];
        c1 += a4.y * W[(4*i+1)*32 + p];
        c2 += a4.z * W[(4*i+2)*32 + p];
        c3 += a4.w * W[(4*i+3)*32 + p];
    }
    out[(m0 + mm)*32 + p] = (c0 + c1) + (c2 + c3);
}

// ---------------- BN stats ----------------
__global__ void bn_stats(const float* __restrict__ xg, float* __restrict__ stats) {
    __shared__ float ls[256], lss[256];
    const int tid = threadIdx.x;
    float s = 0.f, ss = 0.f;
    for (size_t i = (size_t)blockIdx.x*256 + tid; i < (size_t)NN*32; i += (size_t)gridDim.x*256) {
        const float val = xg[i];
        s += val; ss += val * val;
    }
    ls[tid] = s; lss[tid] = ss;
    __syncthreads();
    if (tid < 32) {
        float as_ = 0.f, ass = 0.f;
        #pragma unroll
        for (int w = 0; w < 8; w++) { as_ += ls[tid + 32*w]; ass += lss[tid + 32*w]; }
        atomicAdd(&stats[tid], as_);
        atomicAdd(&stats[32 + tid], ass);
    }
}

// ---------------- BN apply + exact GELU ----------------
__global__ void bn_gelu(const float* __restrict__ xg, const float* __restrict__ stats,
                        const float* __restrict__ bnw, const float* __restrict__ bnb,
                        float* __restrict__ out) {
    const size_t i = (size_t)blockIdx.x * 256 + threadIdx.x;
    const int c = i & 31;
    const float mu = stats[c] * (1.0f / NN);
    const float var = stats[32 + c] * (1.0f / NN) - mu * mu;
    const float xn = bnw[c] * (xg[i] - mu) * rsqrtf(var + EPSV) + bnb[c];
    out[i] = 0.5f * xn * (1.0f + erff(xn * 0.70710678118654752f));
}

// ---------------- hypergraph scatter ----------------
__global__ void hyper_scatter(const float* __restrict__ xh, const int* __restrict__ eidx,
                              float* __restrict__ o1acc, float* __restrict__ degb) {
    const int tid = threadIdx.x;
    const int c = tid & 31;
    const size_t i = (size_t)blockIdx.x * 8 + (tid >> 5);
    const int src = eidx[i];
    const int dst = eidx[NE + i];
    const float xv = xh[i*32 + c];
    atomicAdd(&o1acc[(size_t)src*32 + c], xv);
    atomicAdd(&o1acc[(size_t)dst*32 + c], xv);
    if (c == 0) {
        atomicAdd(&degb[src], 1.0f);
        atomicAdd(&degb[dst], 1.0f);
    }
}

__global__ void o1_finalize(const float* __restrict__ o1acc, const float* __restrict__ degb,
                            const float* __restrict__ attr, float* __restrict__ o1) {
    const size_t i = (size_t)blockIdx.x * 256 + threadIdx.x;
    const int n = (int)(i >> 5);
    const float d = degb[n];
    const float binv = d > 0.f ? 1.0f / d : 0.0f;
    o1[i] = o1acc[i] * binv + attr[i];
}

__global__ void edge_out(const float* __restrict__ o1, const int* __restrict__ eidx,
                         const float* __restrict__ bh, float* __restrict__ out2) {
    const size_t idx = (size_t)blockIdx.x * 256 + threadIdx.x;
    const size_t i = idx >> 5;
    const int c = (int)(idx & 31);
    const int src = eidx[i];
    const int dst = eidx[NE + i];
    out2[idx] = 0.5f * (o1[(size_t)src*32 + c] + o1[(size_t)dst*32 + c]) + bh[c];
}

extern "C" void kernel_launch(void* const* d_in, const int* in_sizes, int n_in,
                              void* d_out, int out_size, void* d_ws, size_t ws_size,
                              hipStream_t stream) {
    const float* x    = (const float*)d_in[0];
    const float* eatt = (const float*)d_in[1];
    const float* Wq   = (const float*)d_in[2];
    const float* bq   = (const float*)d_in[3];
    const float* Wk   = (const float*)d_in[4];
    const float* bk   = (const float*)d_in[5];
    const float* Wv   = (const float*)d_in[6];
    const float* bv   = (const float*)d_in[7];
    const float* We2  = (const float*)d_in[8];
    const float* be2  = (const float*)d_in[9];
    const float* We3  = (const float*)d_in[10];
    const float* be3  = (const float*)d_in[11];
    const float* Wcon = (const float*)d_in[12];
    const float* bnw  = (const float*)d_in[13];
    const float* bnb  = (const float*)d_in[14];
    const float* Wh1  = (const float*)d_in[15];
    const float* Wh2  = (const float*)d_in[16];
    const float* bh   = (const float*)d_in[17];
    const int*   eidx = (const int*)d_in[18];

    float* ws = (float*)d_ws;
    float* q     = ws + OFF_Q;
    float* k     = ws + OFF_K;
    float* v     = ws + OFF_V;
    float* ex1   = ws + OFF_EX1;
    float* ex2   = ws + OFF_EX2;
    float* s1    = ws + OFF_S1;
    float* s2    = ws + OFF_S2;
    float* agg   = ws + OFF_AGG;
    unsigned short* WbT = (unsigned short*)(ws + OFF_WBT);
    float* biasb = ws + OFF_BIASB;
    float* attr  = ws + OFF_ATTR;
    float* o1    = ws + OFF_O1;
    float* xgat  = ws + OFF_XGAT;
    float* o1acc = ws + OFF_O1ACC;
    float* degb  = ws + OFF_DEGB;
    float* stats = ws + OFF_STATS;
    float* xh    = ws + OFF_XH;
    float* out0  = (float*)d_out;
    float* out1  = (float*)d_out + (size_t)NN * 32;

    // zero s1,s2,agg (contiguous)
    hipMemsetAsync(ws + OFF_S1, 0, (38288000UL - OFF_S1) * sizeof(float), stream);

    pack_w<<<129, 256, 0, stream>>>(We2, be2, We3, be3, WbT, biasb);
    qkv_kernel<<<6250, 256, 0, stream>>>(x, Wq, bq, Wk, bk, Wv, bv, q, k, v);

    // fused sweeps: GEMM tile stays in LDS, consumed by the pass logic in-block
    gemm_pass1<<<4000, 256, 0, stream>>>(eatt, WbT, biasb, eidx, q, k, ex1, ex2, s1, s2);
    gemm_pass2<<<4000, 256, 0, stream>>>(eatt, WbT, biasb, eidx, v, ex1, ex2, s1, s2, agg);

    // zero o1acc, degb, stats (contiguous, region1 alias — q/k dead now)
    hipMemsetAsync(ws + OFF_O1ACC, 0, (6450064UL - OFF_O1ACC) * sizeof(float), stream);

    gemm_d128_o32<<<6250, 256, 0, stream>>>(agg, Wcon, xgat);
    bn_stats<<<256, 256, 0, stream>>>(xgat, stats);
    bn_gelu<<<6250, 256, 0, stream>>>(xgat, stats, bnw, bnb, out0);

    gemm_d128_o32<<<32000, 256, 0, stream>>>(eatt, Wh1, xh);
    gemm_d128_o32<<<6250, 256, 0, stream>>>(x, Wh2, attr);
    hyper_scatter<<<32000, 256, 0, stream>>>(xh, eidx, o1acc, degb);
    o1_finalize<<<6250, 256, 0, stream>>>(o1acc, degb, attr, o1);
    edge_out<<<32000, 256, 0, stream>>>(o1, eidx, bh, out1);
}

// Round 4
// 1179.816 us; speedup vs baseline: 1.1902x; 1.1902x over previous
//
#include <hip/hip_runtime.h>
#include <math.h>

#define NN 50000
#define NE 512000
#define NE2 256000
#define SCALE 0.17677669529663687f   // 1/sqrt(32)
#define EPSV 1e-5f

// ---- workspace layout (float offsets) ----
// region1 (dead after attn_pass, then aliased by tail):
#define OFF_Q      0UL          // 50000*128
#define OFF_K      6400000UL
#define OFF_V      12800000UL
//   tail aliases:
#define OFF_ATTR   0UL          // 50000*32
#define OFF_O1     1600000UL
#define OFF_XGAT   3200000UL
#define OFF_O1ACC  4800000UL
#define OFF_DEGB   6400000UL    // 50000
#define OFF_STATS  6450000UL    // 64
// scratch (dead after attn_pass):
#define OFF_EX1    19200000UL   // 512000*4
#define OFF_EX2    21248000UL
#define OFF_XH     19200000UL   // tail alias (ex/Cc2 dead)
#define OFF_CC2    23296000UL   // 512000*128 bf16 = 32768000 floats
#define OFF_CC3    56064000UL   // -> 88832000
// sort arrays (int32):
#define OFF_SEG    88832000UL   // 50001 ints
#define OFF_CUR    88883000UL   // 50000 ints  (zero region start)
#define OFF_CNT    88933000UL   // 50000 ints  (zero region end 88983000)
#define OFF_INV    88983000UL   // 512000 ints
#define OFF_SRCS   89495000UL   // 512000 ints
#define OFF_PART   90007000UL   // 256 ints
#define OFF_WBT    90008000UL   // bf16 256*128 = 32768 ushorts = 16384 floats
#define OFF_BIASB  90024384UL   // 256 floats  (= OFF_WBT + 16384, no overlap)
#define OFF_AGG    90024640UL   // 50000*128 -> 96424640 floats = 385.7 MB

typedef __attribute__((ext_vector_type(8))) short bf16x8;
typedef __attribute__((ext_vector_type(8))) unsigned short us8;
typedef __attribute__((ext_vector_type(4))) float f32x4;

__device__ __forceinline__ unsigned short f2bf(float f) {
    unsigned int u = __float_as_uint(f);
    unsigned int r = (u + 0x7FFFu + ((u >> 16) & 1u)) >> 16;
    return (unsigned short)r;
}
__device__ __forceinline__ float bf2f(unsigned short u) {
    return __uint_as_float(((unsigned int)u) << 16);
}

// ---------------- pack WbT (transposed, bf16) + biasb ----------------
__global__ void pack_w(const float* __restrict__ We2, const float* __restrict__ be2,
                       const float* __restrict__ We3, const float* __restrict__ be3,
                       unsigned short* __restrict__ WbT, float* __restrict__ biasb) {
    const int idx = blockIdx.x * 256 + threadIdx.x;
    if (idx < 32768) {
        const int j = idx >> 7;
        const int k = idx & 127;
        const float w = (j < 128) ? We2[k * 128 + j] : We3[k * 128 + (j - 128)];
        WbT[idx] = f2bf(w);
    } else if (idx < 33024) {
        const int jj = idx - 32768;
        biasb[jj] = (jj < 128) ? be2[jj] : be3[jj - 128];
    }
}

// ---------------- counting sort by dst: hist / scan / scatter ----------------
__global__ void k_hist(const int* __restrict__ eidx, int* __restrict__ cnt) {
    const int e = blockIdx.x * 256 + threadIdx.x;
    atomicAdd(&cnt[eidx[NE + e]], 1);
}

__global__ void k_scanA(const int* __restrict__ cnt, int* __restrict__ seg,
                        int* __restrict__ part) {
    __shared__ int sd[256];
    const int tid = threadIdx.x;
    const int i = blockIdx.x * 256 + tid;
    const int v = (i < NN) ? cnt[i] : 0;
    sd[tid] = v;
    __syncthreads();
    for (int off = 1; off < 256; off <<= 1) {
        int t = (tid >= off) ? sd[tid - off] : 0;
        __syncthreads();
        sd[tid] += t;
        __syncthreads();
    }
    if (i < NN) seg[i] = sd[tid] - v;        // exclusive within block
    if (tid == 255) part[blockIdx.x] = sd[255];
}

__global__ void k_scanB(int* __restrict__ part) {
    __shared__ int sd[256];
    const int tid = threadIdx.x;
    const int v = (tid < 196) ? part[tid] : 0;
    sd[tid] = v;
    __syncthreads();
    for (int off = 1; off < 256; off <<= 1) {
        int t = (tid >= off) ? sd[tid - off] : 0;
        __syncthreads();
        sd[tid] += t;
        __syncthreads();
    }
    if (tid < 196) part[tid] = sd[tid] - v;  // exclusive block offsets
}

__global__ void k_scanC(int* __restrict__ seg, const int* __restrict__ part) {
    const int i = blockIdx.x * 256 + threadIdx.x;
    if (i < NN) seg[i] += part[blockIdx.x];
    if (i == 0) seg[NN] = NE;
}

__global__ void k_scatter(const int* __restrict__ eidx, const int* __restrict__ seg,
                          int* __restrict__ cur, int* __restrict__ inv,
                          int* __restrict__ srcs) {
    const int e = blockIdx.x * 256 + threadIdx.x;
    const int dst = eidx[NE + e];
    const int pos = seg[dst] + atomicAdd(&cur[dst], 1);
    inv[e] = pos;
    srcs[pos] = eidx[e];
}

// ---------------- MFMA GEMM: Cc[inv[e]] = bf16(eatt[e] @ W_half + bias) ----------------
__global__ __launch_bounds__(256)
void gemm_ea(const float* __restrict__ A, const unsigned short* __restrict__ WbT,
             const float* __restrict__ biasb, const int* __restrict__ inv,
             unsigned short* __restrict__ Cc, int half) {
    __shared__ unsigned short As[128 * 72];
    __shared__ unsigned short Bs[128 * 72];
    const int tid = threadIdx.x;
    const int wave = tid >> 6;
    const int lane = tid & 63;
    const int quad = lane >> 4;
    const int l16 = lane & 15;
    const int m0 = (wave & 1) * 64;
    const int n0 = (wave >> 1) * 64;
    const size_t r0 = (size_t)blockIdx.x * 128;

    f32x4 acc[4][4];
    #pragma unroll
    for (int i = 0; i < 4; i++)
        #pragma unroll
        for (int j = 0; j < 4; j++) acc[i][j] = (f32x4){0.f, 0.f, 0.f, 0.f};

    for (int kh = 0; kh < 2; kh++) {
        #pragma unroll
        for (int i = 0; i < 8; i++) {
            const int q = tid + 256 * i;
            const int row = q >> 4;
            const int c4 = q & 15;
            const float4 a4 = *(const float4*)(A + (r0 + row) * 128 + kh * 64 + c4 * 4);
            ushort4 b4;
            b4.x = f2bf(a4.x); b4.y = f2bf(a4.y); b4.z = f2bf(a4.z); b4.w = f2bf(a4.w);
            *(ushort4*)(&As[row * 72 + c4 * 4]) = b4;
        }
        {
            const int n = tid >> 1;
            const int koff = (tid & 1) * 32;
            const unsigned short* src = WbT + (size_t)(half * 128 + n) * 128 + kh * 64 + koff;
            #pragma unroll
            for (int u = 0; u < 4; u++) {
                *(us8*)(&Bs[n * 72 + koff + 8 * u]) = *(const us8*)(src + 8 * u);
            }
        }
        __syncthreads();
        #pragma unroll
        for (int kc = 0; kc < 64; kc += 32) {
            bf16x8 af[4], bf[4];
            #pragma unroll
            for (int i = 0; i < 4; i++)
                af[i] = *(const bf16x8*)(&As[(m0 + 16 * i + l16) * 72 + kc + quad * 8]);
            #pragma unroll
            for (int j = 0; j < 4; j++)
                bf[j] = *(const bf16x8*)(&Bs[(n0 + 16 * j + l16) * 72 + kc + quad * 8]);
            #pragma unroll
            for (int i = 0; i < 4; i++)
                #pragma unroll
                for (int j = 0; j < 4; j++)
                    acc[i][j] = __builtin_amdgcn_mfma_f32_16x16x32_bf16(af[i], bf[j], acc[i][j], 0, 0, 0);
        }
        __syncthreads();
    }
    // epilogue: bias + bf16, scatter rows to sorted positions
    int posr[16];
    #pragma unroll
    for (int i = 0; i < 4; i++)
        #pragma unroll
        for (int r = 0; r < 4; r++)
            posr[i * 4 + r] = inv[r0 + m0 + 16 * i + quad * 4 + r];
    #pragma unroll
    for (int j = 0; j < 4; j++) {
        const int col = n0 + 16 * j + l16;
        const float bcol = biasb[half * 128 + col];
        #pragma unroll
        for (int i = 0; i < 4; i++) {
            #pragma unroll
            for (int r = 0; r < 4; r++) {
                Cc[(size_t)posr[i * 4 + r] * 128 + col] = f2bf(acc[i][j][r] + bcol);
            }
        }
    }
}

// ---------------- K1: q,k,v = x @ W{q,k,v} + b ----------------
__global__ void qkv_kernel(const float* __restrict__ x,
                           const float* __restrict__ Wq, const float* __restrict__ bq,
                           const float* __restrict__ Wk, const float* __restrict__ bk,
                           const float* __restrict__ Wv, const float* __restrict__ bv,
                           float* __restrict__ q, float* __restrict__ k, float* __restrict__ v) {
    __shared__ float xs[8 * 128];
    const int tid = threadIdx.x;
    const int j = tid & 127;
    const int g = tid >> 7;
    const size_t n0 = (size_t)blockIdx.x * 8;
    ((float4*)xs)[tid] = ((const float4*)(x + n0 * 128))[tid];
    __syncthreads();
    float aq[4] = {0,0,0,0}, ak[4] = {0,0,0,0}, av[4] = {0,0,0,0};
    #pragma unroll 4
    for (int d = 0; d < 128; d++) {
        const float wq = Wq[d*128 + j];
        const float wk = Wk[d*128 + j];
        const float wv = Wv[d*128 + j];
        #pragma unroll
        for (int r = 0; r < 4; r++) {
            const float xv = xs[(g + 2*r)*128 + d];
            aq[r] += xv * wq; ak[r] += xv * wk; av[r] += xv * wv;
        }
    }
    const float bqv = bq[j], bkv = bk[j], bvv = bv[j];
    #pragma unroll
    for (int r = 0; r < 4; r++) {
        const size_t n = n0 + g + 2*r;
        q[n*128 + j] = aq[r] + bqv;
        k[n*128 + j] = ak[r] + bkv;
        v[n*128 + j] = av[r] + bvv;
    }
}

// ---------------- fused attention passes: one wave per dst node, ZERO atomics ----------------
__global__ __launch_bounds__(256)
void attn_pass(const int* __restrict__ seg, const int* __restrict__ srcs,
               const float* __restrict__ q, const float* __restrict__ k,
               const float* __restrict__ v,
               const unsigned short* __restrict__ Cc2, const unsigned short* __restrict__ Cc3,
               float* __restrict__ ex1, float* __restrict__ ex2,
               float* __restrict__ agg) {
    const int lane = threadIdx.x & 63;
    const int d = blockIdx.x * 4 + (threadIdx.x >> 6);
    const int s0 = seg[d], s1 = seg[d + 1];
    const float2 qv = ((const float2*)(q + (size_t)d * 128))[lane];
    const int h = lane >> 4;                // head of this lane's channel pair

    // loop 1: logits -> exp, segment sums in registers
    float sh1 = 0.f, sh2 = 0.f;
    for (int i = s0; i < s1; i++) {
        const int src = srcs[i];
        const float2 kv = ((const float2*)(k + (size_t)src * 128))[lane];
        const unsigned int cc = ((const unsigned int*)Cc2)[(size_t)i * 64 + lane];
        float p1 = qv.x * kv.x + qv.y * kv.y;
        float p2 = qv.x * bf2f((unsigned short)(cc & 0xFFFF))
                 + qv.y * bf2f((unsigned short)(cc >> 16));
        #pragma unroll
        for (int off = 8; off > 0; off >>= 1) {
            p1 += __shfl_down(p1, off, 16);
            p2 += __shfl_down(p2, off, 16);
        }
        if ((lane & 15) == 0) {
            const float v1 = __expf(p1 * SCALE);
            const float v2 = __expf(p2 * SCALE);
            ex1[(size_t)i * 4 + h] = v1;
            ex2[(size_t)i * 4 + h] = v2;
            sh1 += v1; sh2 += v2;
        }
    }
    const float r1 = 1.f / (sh1 + 1e-16f);
    const float r2 = 1.f / (sh2 + 1e-16f);
    const float i1 = __shfl(r1, h * 16);
    const float i2 = __shfl(r2, h * 16);

    // loop 2: aggregate alpha1*v + alpha2*ea3 in registers
    float ax = 0.f, ay = 0.f;
    for (int i = s0; i < s1; i++) {
        const int src = srcs[i];
        const float2 vv = ((const float2*)(v + (size_t)src * 128))[lane];
        const unsigned int c3 = ((const unsigned int*)Cc3)[(size_t)i * 64 + lane];
        const float a1 = ex1[(size_t)i * 4 + h] * i1;
        const float a2 = ex2[(size_t)i * 4 + h] * i2;
        ax += a1 * vv.x + a2 * bf2f((unsigned short)(c3 & 0xFFFF));
        ay += a1 * vv.y + a2 * bf2f((unsigned short)(c3 >> 16));
    }
    ((float2*)(agg + (size_t)d * 128))[lane] = (float2){ax, ay};
}

// ---------------- generic (M x 128) @ (128 x 32) ----------------
__global__ void gemm_d128_o32(const float* __restrict__ A, const float* __restrict__ W,
                              float* __restrict__ out) {
    __shared__ float as[8 * 128];
    const int tid = threadIdx.x;
    const int p = tid & 31;
    const int mm = tid >> 5;
    const size_t m0 = (size_t)blockIdx.x * 8;
    ((float4*)as)[tid] = ((const float4*)(A + m0 * 128))[tid];
    __syncthreads();
    float c0 = 0.f, c1 = 0.f, c2 = 0.f, c3 = 0.f;
    const float4* as4 = (const float4*)as;
    #pragma unroll 8
    for (int i = 0; i < 32; i++) {
        const float4 a4 = as4[mm*32 + i];
        c0 += a4.x * W[(4*i+0)*32 + p];
        c1 += a4.y * W[(4*i+1)*32 + p];
        c2 += a4.z * W[(4*i+2)*32 + p];
        c3 += a4.w * W[(4*i+3)*32 + p];
    }
    out[(m0 + mm)*32 + p] = (c0 + c1) + (c2 + c3);
}

// ---------------- BN stats ----------------
__global__ void bn_stats(const float* __restrict__ xg, float* __restrict__ stats) {
    __shared__ float ls[256], lss[256];
    const int tid = threadIdx.x;
    float s = 0.f, ss = 0.f;
    for (size_t i = (size_t)blockIdx.x*256 + tid; i < (size_t)NN*32; i += (size_t)gridDim.x*256) {
        const float val = xg[i];
        s += val; ss += val * val;
    }
    ls[tid] = s; lss[tid] = ss;
    __syncthreads();
    if (tid < 32) {
        float as_ = 0.f, ass = 0.f;
        #pragma unroll
        for (int w = 0; w < 8; w++) { as_ += ls[tid + 32*w]; ass += lss[tid + 32*w]; }
        atomicAdd(&stats[tid], as_);
        atomicAdd(&stats[32 + tid], ass);
    }
}

// ---------------- BN apply + exact GELU ----------------
__global__ void bn_gelu(const float* __restrict__ xg, const float* __restrict__ stats,
                        const float* __restrict__ bnw, const float* __restrict__ bnb,
                        float* __restrict__ out) {
    const size_t i = (size_t)blockIdx.x * 256 + threadIdx.x;
    const int c = i & 31;
    const float mu = stats[c] * (1.0f / NN);
    const float var = stats[32 + c] * (1.0f / NN) - mu * mu;
    const float xn = bnw[c] * (xg[i] - mu) * rsqrtf(var + EPSV) + bnb[c];
    out[i] = 0.5f * xn * (1.0f + erff(xn * 0.70710678118654752f));
}

// ---------------- hypergraph scatter ----------------
__global__ void hyper_scatter(const float* __restrict__ xh, const int* __restrict__ eidx,
                              float* __restrict__ o1acc, float* __restrict__ degb) {
    const int tid = threadIdx.x;
    const int c = tid & 31;
    const size_t i = (size_t)blockIdx.x * 8 + (tid >> 5);
    const int src = eidx[i];
    const int dst = eidx[NE + i];
    const float xv = xh[i*32 + c];
    atomicAdd(&o1acc[(size_t)src*32 + c], xv);
    atomicAdd(&o1acc[(size_t)dst*32 + c], xv);
    if (c == 0) {
        atomicAdd(&degb[src], 1.0f);
        atomicAdd(&degb[dst], 1.0f);
    }
}

__global__ void o1_finalize(const float* __restrict__ o1acc, const float* __restrict__ degb,
                            const float* __restrict__ attr, float* __restrict__ o1) {
    const size_t i = (size_t)blockIdx.x * 256 + threadIdx.x;
    const int n = (int)(i >> 5);
    const float d = degb[n];
    const float binv = d > 0.f ? 1.0f / d : 0.0f;
    o1[i] = o1acc[i] * binv + attr[i];
}

__global__ void edge_out(const float* __restrict__ o1, const int* __restrict__ eidx,
                         const float* __restrict__ bh, float* __restrict__ out2) {
    const size_t idx = (size_t)blockIdx.x * 256 + threadIdx.x;
    const size_t i = idx >> 5;
    const int c = (int)(idx & 31);
    const int src = eidx[i];
    const int dst = eidx[NE + i];
    out2[idx] = 0.5f * (o1[(size_t)src*32 + c] + o1[(size_t)dst*32 + c]) + bh[c];
}

extern "C" void kernel_launch(void* const* d_in, const int* in_sizes, int n_in,
                              void* d_out, int out_size, void* d_ws, size_t ws_size,
                              hipStream_t stream) {
    const float* x    = (const float*)d_in[0];
    const float* eatt = (const float*)d_in[1];
    const float* Wq   = (const float*)d_in[2];
    const float* bq   = (const float*)d_in[3];
    const float* Wk   = (const float*)d_in[4];
    const float* bk   = (const float*)d_in[5];
    const float* Wv   = (const float*)d_in[6];
    const float* bv   = (const float*)d_in[7];
    const float* We2  = (const float*)d_in[8];
    const float* be2  = (const float*)d_in[9];
    const float* We3  = (const float*)d_in[10];
    const float* be3  = (const float*)d_in[11];
    const float* Wcon = (const float*)d_in[12];
    const float* bnw  = (const float*)d_in[13];
    const float* bnb  = (const float*)d_in[14];
    const float* Wh1  = (const float*)d_in[15];
    const float* Wh2  = (const float*)d_in[16];
    const float* bh   = (const float*)d_in[17];
    const int*   eidx = (const int*)d_in[18];

    float* ws = (float*)d_ws;
    float* q     = ws + OFF_Q;
    float* k     = ws + OFF_K;
    float* v     = ws + OFF_V;
    float* ex1   = ws + OFF_EX1;
    float* ex2   = ws + OFF_EX2;
    unsigned short* Cc2 = (unsigned short*)(ws + OFF_CC2);
    unsigned short* Cc3 = (unsigned short*)(ws + OFF_CC3);
    int* seg  = (int*)(ws + OFF_SEG);
    int* cur  = (int*)(ws + OFF_CUR);
    int* cnt  = (int*)(ws + OFF_CNT);
    int* inv  = (int*)(ws + OFF_INV);
    int* srcs = (int*)(ws + OFF_SRCS);
    int* part = (int*)(ws + OFF_PART);
    unsigned short* WbT = (unsigned short*)(ws + OFF_WBT);
    float* biasb = ws + OFF_BIASB;
    float* agg   = ws + OFF_AGG;
    float* attr  = ws + OFF_ATTR;
    float* o1    = ws + OFF_O1;
    float* xgat  = ws + OFF_XGAT;
    float* o1acc = ws + OFF_O1ACC;
    float* degb  = ws + OFF_DEGB;
    float* stats = ws + OFF_STATS;
    float* xh    = ws + OFF_XH;
    float* out0  = (float*)d_out;
    float* out1  = (float*)d_out + (size_t)NN * 32;

    // zero cur+cnt (contiguous 100000 ints)
    hipMemsetAsync(ws + OFF_CUR, 0, 100000 * sizeof(int), stream);

    pack_w<<<129, 256, 0, stream>>>(We2, be2, We3, be3, WbT, biasb);

    // counting sort by dst
    k_hist<<<2000, 256, 0, stream>>>(eidx, cnt);
    k_scanA<<<196, 256, 0, stream>>>(cnt, seg, part);
    k_scanB<<<1, 256, 0, stream>>>(part);
    k_scanC<<<196, 256, 0, stream>>>(seg, part);
    k_scatter<<<2000, 256, 0, stream>>>(eidx, seg, cur, inv, srcs);

    qkv_kernel<<<6250, 256, 0, stream>>>(x, Wq, bq, Wk, bk, Wv, bv, q, k, v);

    // GEMMs write bf16 rows directly to dst-sorted positions
    gemm_ea<<<4000, 256, 0, stream>>>(eatt, WbT, biasb, inv, Cc2, 0);
    gemm_ea<<<4000, 256, 0, stream>>>(eatt, WbT, biasb, inv, Cc3, 1);

    // fused softmax+aggregate: one wave per dst node, no atomics
    attn_pass<<<12500, 256, 0, stream>>>(seg, srcs, q, k, v, Cc2, Cc3, ex1, ex2, agg);

    // zero o1acc, degb, stats (contiguous, region1 alias — q/k dead now)
    hipMemsetAsync(ws + OFF_O1ACC, 0, (6450064UL - OFF_O1ACC) * sizeof(float), stream);

    gemm_d128_o32<<<6250, 256, 0, stream>>>(agg, Wcon, xgat);
    bn_stats<<<256, 256, 0, stream>>>(xgat, stats);
    bn_gelu<<<6250, 256, 0, stream>>>(xgat, stats, bnw, bnb, out0);

    gemm_d128_o32<<<32000, 256, 0, stream>>>(eatt, Wh1, xh);
    gemm_d128_o32<<<6250, 256, 0, stream>>>(x, Wh2, attr);
    hyper_scatter<<<32000, 256, 0, stream>>>(xh, eidx, o1acc, degb);
    o1_finalize<<<6250, 256, 0, stream>>>(o1acc, degb, attr, o1);
    edge_out<<<32000, 256, 0, stream>>>(o1, eidx, bh, out1);
}

// Round 5
// 1069.408 us; speedup vs baseline: 1.3130x; 1.1032x over previous
//
#include <hip/hip_runtime.h>
#include <math.h>

#define NN 50000
#define NE 512000
#define NE2 256000
#define SCALE 0.17677669529663687f   // 1/sqrt(32)
#define EPSV 1e-5f

// ---- workspace layout (float offsets) ----
// region1 (dead after attn_pass, then aliased by tail):
#define OFF_Q      0UL          // 50000*128
#define OFF_K      6400000UL
#define OFF_V      12800000UL
//   tail aliases:
#define OFF_ATTR   0UL          // 50000*32
#define OFF_O1     1600000UL
#define OFF_XGAT   3200000UL
#define OFF_O1ACC  4800000UL
#define OFF_DEGB   6400000UL    // 50000
#define OFF_STATS  6450000UL    // 64
// scratch (dead after attn_pass):
#define OFF_XH     19200000UL   // tail alias
#define OFF_CC2    23296000UL   // 512000*128 bf16 = 32768000 floats
#define OFF_CC3    56064000UL   // -> 88832000
// sort arrays (int32):
#define OFF_SEG    88832000UL   // 50001 ints
#define OFF_CUR    88883000UL   // 50000 ints  (zero region start)
#define OFF_CNT    88933000UL   // 50000 ints  (zero region end 88983000)
#define OFF_INV    88983000UL   // 512000 ints
#define OFF_SRCS   89495000UL   // 512000 ints
#define OFF_PART   90007000UL   // 256 ints
#define OFF_WBT    90008000UL   // bf16 256*128 = 32768 ushorts = 16384 floats
#define OFF_BIASB  90024384UL   // 256 floats  (= OFF_WBT + 16384, no overlap)
#define OFF_AGG    90024640UL   // 50000*128 -> 96424640 floats = 385.7 MB

typedef __attribute__((ext_vector_type(8))) short bf16x8;
typedef __attribute__((ext_vector_type(8))) unsigned short us8;
typedef __attribute__((ext_vector_type(4))) float f32x4;

__device__ __forceinline__ unsigned short f2bf(float f) {
    unsigned int u = __float_as_uint(f);
    unsigned int r = (u + 0x7FFFu + ((u >> 16) & 1u)) >> 16;
    return (unsigned short)r;
}
__device__ __forceinline__ float bf2f(unsigned short u) {
    return __uint_as_float(((unsigned int)u) << 16);
}

// ---------------- pack WbT (transposed, bf16) + biasb ----------------
__global__ void pack_w(const float* __restrict__ We2, const float* __restrict__ be2,
                       const float* __restrict__ We3, const float* __restrict__ be3,
                       unsigned short* __restrict__ WbT, float* __restrict__ biasb) {
    const int idx = blockIdx.x * 256 + threadIdx.x;
    if (idx < 32768) {
        const int j = idx >> 7;
        const int k = idx & 127;
        const float w = (j < 128) ? We2[k * 128 + j] : We3[k * 128 + (j - 128)];
        WbT[idx] = f2bf(w);
    } else if (idx < 33024) {
        const int jj = idx - 32768;
        biasb[jj] = (jj < 128) ? be2[jj] : be3[jj - 128];
    }
}

// ---------------- counting sort by dst: hist / scan / scatter ----------------
__global__ void k_hist(const int* __restrict__ eidx, int* __restrict__ cnt) {
    const int e = blockIdx.x * 256 + threadIdx.x;
    atomicAdd(&cnt[eidx[NE + e]], 1);
}

__global__ void k_scanA(const int* __restrict__ cnt, int* __restrict__ seg,
                        int* __restrict__ part) {
    __shared__ int sd[256];
    const int tid = threadIdx.x;
    const int i = blockIdx.x * 256 + tid;
    const int v = (i < NN) ? cnt[i] : 0;
    sd[tid] = v;
    __syncthreads();
    for (int off = 1; off < 256; off <<= 1) {
        int t = (tid >= off) ? sd[tid - off] : 0;
        __syncthreads();
        sd[tid] += t;
        __syncthreads();
    }
    if (i < NN) seg[i] = sd[tid] - v;        // exclusive within block
    if (tid == 255) part[blockIdx.x] = sd[255];
}

__global__ void k_scanB(int* __restrict__ part) {
    __shared__ int sd[256];
    const int tid = threadIdx.x;
    const int v = (tid < 196) ? part[tid] : 0;
    sd[tid] = v;
    __syncthreads();
    for (int off = 1; off < 256; off <<= 1) {
        int t = (tid >= off) ? sd[tid - off] : 0;
        __syncthreads();
        sd[tid] += t;
        __syncthreads();
    }
    if (tid < 196) part[tid] = sd[tid] - v;  // exclusive block offsets
}

__global__ void k_scanC(int* __restrict__ seg, const int* __restrict__ part) {
    const int i = blockIdx.x * 256 + threadIdx.x;
    if (i < NN) seg[i] += part[blockIdx.x];
    if (i == 0) seg[NN] = NE;
}

__global__ void k_scatter(const int* __restrict__ eidx, const int* __restrict__ seg,
                          int* __restrict__ cur, int* __restrict__ inv,
                          int* __restrict__ srcs) {
    const int e = blockIdx.x * 256 + threadIdx.x;
    const int dst = eidx[NE + e];
    const int pos = seg[dst] + atomicAdd(&cur[dst], 1);
    inv[e] = pos;
    srcs[pos] = eidx[e];
}

// ---------------- MFMA GEMM (both halves): Cc2/Cc3[inv[e]] = bf16(eatt[e] @ W + bias) --------
// tile 128(M) x 256(N): A staged ONCE for both output halves. 4 waves: 2M x 2Nhalf.
__global__ __launch_bounds__(256)
void gemm_ea2(const float* __restrict__ A, const unsigned short* __restrict__ WbT,
              const float* __restrict__ biasb, const int* __restrict__ inv,
              unsigned short* __restrict__ Cc2, unsigned short* __restrict__ Cc3) {
    __shared__ unsigned short As[128 * 72];   // 9216
    __shared__ unsigned short Bs[256 * 72];   // 18432
    const int tid = threadIdx.x;
    const int wave = tid >> 6;
    const int lane = tid & 63;
    const int quad = lane >> 4;
    const int l16 = lane & 15;
    const int m0 = (wave & 1) * 64;
    const int half = wave >> 1;               // 0 -> Cc2 cols, 1 -> Cc3 cols
    const int n0g = half * 128;
    const size_t r0 = (size_t)blockIdx.x * 128;

    f32x4 acc[4][8];
    #pragma unroll
    for (int i = 0; i < 4; i++)
        #pragma unroll
        for (int j = 0; j < 8; j++) acc[i][j] = (f32x4){0.f, 0.f, 0.f, 0.f};

    for (int kh = 0; kh < 2; kh++) {
        // stage A half: 128 rows x 64 cols fp32 -> bf16
        #pragma unroll
        for (int i = 0; i < 8; i++) {
            const int qq = tid + 256 * i;
            const int row = qq >> 4;
            const int c4 = qq & 15;
            const float4 a4 = *(const float4*)(A + (r0 + row) * 128 + kh * 64 + c4 * 4);
            ushort4 b4;
            b4.x = f2bf(a4.x); b4.y = f2bf(a4.y); b4.z = f2bf(a4.z); b4.w = f2bf(a4.w);
            *(ushort4*)(&As[row * 72 + c4 * 4]) = b4;
        }
        // stage B half: 256 rows (both weight halves), 64 ushorts each; 1 thread per row
        {
            const unsigned short* src = WbT + (size_t)tid * 128 + kh * 64;
            #pragma unroll
            for (int u = 0; u < 8; u++) {
                *(us8*)(&Bs[tid * 72 + 8 * u]) = *(const us8*)(src + 8 * u);
            }
        }
        __syncthreads();
        #pragma unroll
        for (int kc = 0; kc < 64; kc += 32) {
            bf16x8 af[4], bf[8];
            #pragma unroll
            for (int i = 0; i < 4; i++)
                af[i] = *(const bf16x8*)(&As[(m0 + 16 * i + l16) * 72 + kc + quad * 8]);
            #pragma unroll
            for (int j = 0; j < 8; j++)
                bf[j] = *(const bf16x8*)(&Bs[(n0g + 16 * j + l16) * 72 + kc + quad * 8]);
            #pragma unroll
            for (int i = 0; i < 4; i++)
                #pragma unroll
                for (int j = 0; j < 8; j++)
                    acc[i][j] = __builtin_amdgcn_mfma_f32_16x16x32_bf16(af[i], bf[j], acc[i][j], 0, 0, 0);
        }
        __syncthreads();
    }
    // epilogue: bias + bf16, scatter rows to sorted positions
    unsigned short* __restrict__ Cc = half ? Cc3 : Cc2;
    int posr[16];
    #pragma unroll
    for (int i = 0; i < 4; i++)
        #pragma unroll
        for (int r = 0; r < 4; r++)
            posr[i * 4 + r] = inv[r0 + m0 + 16 * i + quad * 4 + r];
    #pragma unroll
    for (int j = 0; j < 8; j++) {
        const int col = 16 * j + l16;                  // local col within the half
        const float bcol = biasb[n0g + col];
        #pragma unroll
        for (int i = 0; i < 4; i++) {
            #pragma unroll
            for (int r = 0; r < 4; r++) {
                Cc[(size_t)posr[i * 4 + r] * 128 + col] = f2bf(acc[i][j][r] + bcol);
            }
        }
    }
}

// ---------------- K1: q,k,v = x @ W{q,k,v} + b ----------------
__global__ void qkv_kernel(const float* __restrict__ x,
                           const float* __restrict__ Wq, const float* __restrict__ bq,
                           const float* __restrict__ Wk, const float* __restrict__ bk,
                           const float* __restrict__ Wv, const float* __restrict__ bv,
                           float* __restrict__ q, float* __restrict__ k, float* __restrict__ v) {
    __shared__ float xs[8 * 128];
    const int tid = threadIdx.x;
    const int j = tid & 127;
    const int g = tid >> 7;
    const size_t n0 = (size_t)blockIdx.x * 8;
    ((float4*)xs)[tid] = ((const float4*)(x + n0 * 128))[tid];
    __syncthreads();
    float aq[4] = {0,0,0,0}, ak[4] = {0,0,0,0}, av[4] = {0,0,0,0};
    #pragma unroll 4
    for (int d = 0; d < 128; d++) {
        const float wq = Wq[d*128 + j];
        const float wk = Wk[d*128 + j];
        const float wv = Wv[d*128 + j];
        #pragma unroll
        for (int r = 0; r < 4; r++) {
            const float xv = xs[(g + 2*r)*128 + d];
            aq[r] += xv * wq; ak[r] += xv * wk; av[r] += xv * wv;
        }
    }
    const float bqv = bq[j], bkv = bk[j], bvv = bv[j];
    #pragma unroll
    for (int r = 0; r < 4; r++) {
        const size_t n = n0 + g + 2*r;
        q[n*128 + j] = aq[r] + bqv;
        k[n*128 + j] = ak[r] + bkv;
        v[n*128 + j] = av[r] + bvv;
    }
}

// ---------------- fused attention, SINGLE loop: deferred normalization, zero atomics --------
// one wave per dst node; per lane: channels (2*lane, 2*lane+1); head = lane>>4
__global__ __launch_bounds__(256)
void attn_pass(const int* __restrict__ seg, const int* __restrict__ srcs,
               const float* __restrict__ q, const float* __restrict__ k,
               const float* __restrict__ v,
               const unsigned short* __restrict__ Cc2, const unsigned short* __restrict__ Cc3,
               float* __restrict__ agg) {
    const int lane = threadIdx.x & 63;
    const int d = blockIdx.x * 4 + (threadIdx.x >> 6);
    const int s0 = seg[d], s1e = seg[d + 1];
    const float2 qv = ((const float2*)(q + (size_t)d * 128))[lane];

    float axv = 0.f, ayv = 0.f;    // sum ex1 * v
    float axe = 0.f, aye = 0.f;    // sum ex2 * ea3
    float sh1 = 0.f, sh2 = 0.f;    // segment sums of ex1, ex2 (per head, replicated)

    // 1-ahead prefetch of the gathered rows
    float2 kv_c = {0.f, 0.f}, vv_c = {0.f, 0.f};
    unsigned int cc_c = 0, c3_c = 0;
    if (s0 < s1e) {
        const int sc = srcs[s0];
        kv_c = ((const float2*)(k + (size_t)sc * 128))[lane];
        vv_c = ((const float2*)(v + (size_t)sc * 128))[lane];
        cc_c = ((const unsigned int*)Cc2)[(size_t)s0 * 64 + lane];
        c3_c = ((const unsigned int*)Cc3)[(size_t)s0 * 64 + lane];
    }
    for (int i = s0; i < s1e; i++) {
        float2 kv_n = {0.f, 0.f}, vv_n = {0.f, 0.f};
        unsigned int cc_n = 0, c3_n = 0;
        if (i + 1 < s1e) {
            const int sn = srcs[i + 1];
            kv_n = ((const float2*)(k + (size_t)sn * 128))[lane];
            vv_n = ((const float2*)(v + (size_t)sn * 128))[lane];
            cc_n = ((const unsigned int*)Cc2)[(size_t)(i + 1) * 64 + lane];
            c3_n = ((const unsigned int*)Cc3)[(size_t)(i + 1) * 64 + lane];
        }
        float p1 = qv.x * kv_c.x + qv.y * kv_c.y;
        float p2 = qv.x * bf2f((unsigned short)(cc_c & 0xFFFF))
                 + qv.y * bf2f((unsigned short)(cc_c >> 16));
        #pragma unroll
        for (int off = 8; off > 0; off >>= 1) {
            p1 += __shfl_xor(p1, off, 16);
            p2 += __shfl_xor(p2, off, 16);
        }
        const float e1 = __expf(p1 * SCALE);   // identical across the 16 lanes of the head
        const float e2 = __expf(p2 * SCALE);
        sh1 += e1; sh2 += e2;
        axv += e1 * vv_c.x;  ayv += e1 * vv_c.y;
        axe += e2 * bf2f((unsigned short)(c3_c & 0xFFFF));
        aye += e2 * bf2f((unsigned short)(c3_c >> 16));
        kv_c = kv_n; vv_c = vv_n; cc_c = cc_n; c3_c = c3_n;
    }
    const float r1 = 1.f / (sh1 + 1e-16f);
    const float r2 = 1.f / (sh2 + 1e-16f);
    ((float2*)(agg + (size_t)d * 128))[lane] = (float2){axv * r1 + axe * r2,
                                                        ayv * r1 + aye * r2};
}

// ---------------- generic (M x 128) @ (128 x 32) ----------------
__global__ void gemm_d128_o32(const float* __restrict__ A, const float* __restrict__ W,
                              float* __restrict__ out) {
    __shared__ float as[8 * 128];
    const int tid = threadIdx.x;
    const int p = tid & 31;
    const int mm = tid >> 5;
    const size_t m0 = (size_t)blockIdx.x * 8;
    ((float4*)as)[tid] = ((const float4*)(A + m0 * 128))[tid];
    __syncthreads();
    float c0 = 0.f, c1 = 0.f, c2 = 0.f, c3 = 0.f;
    const float4* as4 = (const float4*)as;
    #pragma unroll 8
    for (int i = 0; i < 32; i++) {
        const float4 a4 = as4[mm*32 + i];
        c0 += a4.x * W[(4*i+0)*32 + p];
        c1 += a4.y * W[(4*i+1)*32 + p];
        c2 += a4.z * W[(4*i+2)*32 + p];
        c3 += a4.w * W[(4*i+3)*32 + p];
    }
    out[(m0 + mm)*32 + p] = (c0 + c1) + (c2 + c3);
}

// ---------------- BN stats ----------------
__global__ void bn_stats(const float* __restrict__ xg, float* __restrict__ stats) {
    __shared__ float ls[256], lss[256];
    const int tid = threadIdx.x;
    float s = 0.f, ss = 0.f;
    for (size_t i = (size_t)blockIdx.x*256 + tid; i < (size_t)NN*32; i += (size_t)gridDim.x*256) {
        const float val = xg[i];
        s += val; ss += val * val;
    }
    ls[tid] = s; lss[tid] = ss;
    __syncthreads();
    if (tid < 32) {
        float as_ = 0.f, ass = 0.f;
        #pragma unroll
        for (int w = 0; w < 8; w++) { as_ += ls[tid + 32*w]; ass += lss[tid + 32*w]; }
        atomicAdd(&stats[tid], as_);
        atomicAdd(&stats[32 + tid], ass);
    }
}

// ---------------- BN apply + exact GELU ----------------
__global__ void bn_gelu(const float* __restrict__ xg, const float* __restrict__ stats,
                        const float* __restrict__ bnw, const float* __restrict__ bnb,
                        float* __restrict__ out) {
    const size_t i = (size_t)blockIdx.x * 256 + threadIdx.x;
    const int c = i & 31;
    const float mu = stats[c] * (1.0f / NN);
    const float var = stats[32 + c] * (1.0f / NN) - mu * mu;
    const float xn = bnw[c] * (xg[i] - mu) * rsqrtf(var + EPSV) + bnb[c];
    out[i] = 0.5f * xn * (1.0f + erff(xn * 0.70710678118654752f));
}

// ---------------- hypergraph scatter ----------------
__global__ void hyper_scatter(const float* __restrict__ xh, const int* __restrict__ eidx,
                              float* __restrict__ o1acc, float* __restrict__ degb) {
    const int tid = threadIdx.x;
    const int c = tid & 31;
    const size_t i = (size_t)blockIdx.x * 8 + (tid >> 5);
    const int src = eidx[i];
    const int dst = eidx[NE + i];
    const float xv = xh[i*32 + c];
    atomicAdd(&o1acc[(size_t)src*32 + c], xv);
    atomicAdd(&o1acc[(size_t)dst*32 + c], xv);
    if (c == 0) {
        atomicAdd(&degb[src], 1.0f);
        atomicAdd(&degb[dst], 1.0f);
    }
}

__global__ void o1_finalize(const float* __restrict__ o1acc, const float* __restrict__ degb,
                            const float* __restrict__ attr, float* __restrict__ o1) {
    const size_t i = (size_t)blockIdx.x * 256 + threadIdx.x;
    const int n = (int)(i >> 5);
    const float d = degb[n];
    const float binv = d > 0.f ? 1.0f / d : 0.0f;
    o1[i] = o1acc[i] * binv + attr[i];
}

__global__ void edge_out(const float* __restrict__ o1, const int* __restrict__ eidx,
                         const float* __restrict__ bh, float* __restrict__ out2) {
    const size_t idx = (size_t)blockIdx.x * 256 + threadIdx.x;
    const size_t i = idx >> 5;
    const int c = (int)(idx & 31);
    const int src = eidx[i];
    const int dst = eidx[NE + i];
    out2[idx] = 0.5f * (o1[(size_t)src*32 + c] + o1[(size_t)dst*32 + c]) + bh[c];
}

extern "C" void kernel_launch(void* const* d_in, const int* in_sizes, int n_in,
                              void* d_out, int out_size, void* d_ws, size_t ws_size,
                              hipStream_t stream) {
    const float* x    = (const float*)d_in[0];
    const float* eatt = (const float*)d_in[1];
    const float* Wq   = (const float*)d_in[2];
    const float* bq   = (const float*)d_in[3];
    const float* Wk   = (const float*)d_in[4];
    const float* bk   = (const float*)d_in[5];
    const float* Wv   = (const float*)d_in[6];
    const float* bv   = (const float*)d_in[7];
    const float* We2  = (const float*)d_in[8];
    const float* be2  = (const float*)d_in[9];
    const float* We3  = (const float*)d_in[10];
    const float* be3  = (const float*)d_in[11];
    const float* Wcon = (const float*)d_in[12];
    const float* bnw  = (const float*)d_in[13];
    const float* bnb  = (const float*)d_in[14];
    const float* Wh1  = (const float*)d_in[15];
    const float* Wh2  = (const float*)d_in[16];
    const float* bh   = (const float*)d_in[17];
    const int*   eidx = (const int*)d_in[18];

    float* ws = (float*)d_ws;
    float* q     = ws + OFF_Q;
    float* k     = ws + OFF_K;
    float* v     = ws + OFF_V;
    unsigned short* Cc2 = (unsigned short*)(ws + OFF_CC2);
    unsigned short* Cc3 = (unsigned short*)(ws + OFF_CC3);
    int* seg  = (int*)(ws + OFF_SEG);
    int* cur  = (int*)(ws + OFF_CUR);
    int* cnt  = (int*)(ws + OFF_CNT);
    int* inv  = (int*)(ws + OFF_INV);
    int* srcs = (int*)(ws + OFF_SRCS);
    int* part = (int*)(ws + OFF_PART);
    unsigned short* WbT = (unsigned short*)(ws + OFF_WBT);
    float* biasb = ws + OFF_BIASB;
    float* agg   = ws + OFF_AGG;
    float* attr  = ws + OFF_ATTR;
    float* o1    = ws + OFF_O1;
    float* xgat  = ws + OFF_XGAT;
    float* o1acc = ws + OFF_O1ACC;
    float* degb  = ws + OFF_DEGB;
    float* stats = ws + OFF_STATS;
    float* xh    = ws + OFF_XH;
    float* out0  = (float*)d_out;
    float* out1  = (float*)d_out + (size_t)NN * 32;

    // zero cur+cnt (contiguous 100000 ints)
    hipMemsetAsync(ws + OFF_CUR, 0, 100000 * sizeof(int), stream);

    pack_w<<<129, 256, 0, stream>>>(We2, be2, We3, be3, WbT, biasb);

    // counting sort by dst
    k_hist<<<2000, 256, 0, stream>>>(eidx, cnt);
    k_scanA<<<196, 256, 0, stream>>>(cnt, seg, part);
    k_scanB<<<1, 256, 0, stream>>>(part);
    k_scanC<<<196, 256, 0, stream>>>(seg, part);
    k_scatter<<<2000, 256, 0, stream>>>(eidx, seg, cur, inv, srcs);

    qkv_kernel<<<6250, 256, 0, stream>>>(x, Wq, bq, Wk, bk, Wv, bv, q, k, v);

    // single GEMM stages A once, writes BOTH bf16 outputs to dst-sorted positions
    gemm_ea2<<<4000, 256, 0, stream>>>(eatt, WbT, biasb, inv, Cc2, Cc3);

    // fused softmax+aggregate: one wave per dst node, single loop, no atomics
    attn_pass<<<12500, 256, 0, stream>>>(seg, srcs, q, k, v, Cc2, Cc3, agg);

    // zero o1acc, degb, stats (contiguous, region1 alias — q/k dead now)
    hipMemsetAsync(ws + OFF_O1ACC, 0, (6450064UL - OFF_O1ACC) * sizeof(float), stream);

    gemm_d128_o32<<<6250, 256, 0, stream>>>(agg, Wcon, xgat);
    bn_stats<<<256, 256, 0, stream>>>(xgat, stats);
    bn_gelu<<<6250, 256, 0, stream>>>(xgat, stats, bnw, bnb, out0);

    gemm_d128_o32<<<32000, 256, 0, stream>>>(eatt, Wh1, xh);
    gemm_d128_o32<<<6250, 256, 0, stream>>>(x, Wh2, attr);
    hyper_scatter<<<32000, 256, 0, stream>>>(xh, eidx, o1acc, degb);
    o1_finalize<<<6250, 256, 0, stream>>>(o1acc, degb, attr, o1);
    edge_out<<<32000, 256, 0, stream>>>(o1, eidx, bh, out1);
}